// Round 3
// baseline (321.538 us; speedup 1.0000x reference)
//
#include <hip/hip_runtime.h>
#include <hip/hip_bf16.h>
#include <cstdint>

// ---------------------------------------------------------------------------
// SelfAttention: q,k,v = x@W{q,k,v}^T + b ; P = softmax(qk^T/sqrt(H)) ; out = P@v
// B=4, S=2048, H=I=1024. fp32 I/O, bf16 MFMA internally (tol 6.25e-3).
// R3: 32x32x16 MFMA (2x FLOP/inst, faster pipe), merged convert kernel.
//     Kept from R2: BK=64, XOR-swizzled LDS (0 bank conflicts), fused QKV.
// ---------------------------------------------------------------------------

typedef __bf16 bf16x8  __attribute__((ext_vector_type(8)));
typedef float  f32x16  __attribute__((ext_vector_type(16)));

__device__ __forceinline__ void load_lds16(const __bf16* g, __bf16* l) {
    __builtin_amdgcn_global_load_lds(
        (const __attribute__((address_space(1))) void*)g,
        (__attribute__((address_space(3))) void*)l,
        16, 0, 0);
}

// ------------- merged fp32->bf16 converts + bias pack (1 launch) -----------
// chunks of 8 floats: x: 1048576 | Wq/Wk/Wv: 131072 each | bias3: 384
__global__ __launch_bounds__(256) void cvt_all(
        const float* __restrict__ x,
        const float* __restrict__ wq, const float* __restrict__ wk,
        const float* __restrict__ wv,
        const float* __restrict__ bq, const float* __restrict__ bk,
        const float* __restrict__ bv,
        __bf16* __restrict__ xb, __bf16* __restrict__ wb,
        float* __restrict__ bias3) {
    const long NX = 1048576, NW = 131072;
    long i = (long)blockIdx.x * 256 + threadIdx.x;
    const float* src; __bf16* dst; long c;
    if (i < NX) { src = x; dst = xb; c = i; }
    else if (i < NX + 3 * NW) {
        long j = i - NX;
        src = (j < NW) ? wq : (j < 2 * NW) ? wk : wv;
        c = j % NW;
        dst = wb + (j / NW) * (NW * 8);
    } else if (i < NX + 3 * NW + 384) {
        long cidx = i - (NX + 3 * NW);
        int seg = (int)(cidx >> 7);                  // 128 chunks per segment
        const float* bs = (seg == 0) ? bq : (seg == 1) ? bk : bv;
        long off = (cidx & 127) * 8;
        float4 a = *(const float4*)(bs + off);
        float4 b = *(const float4*)(bs + off + 4);
        *(float4*)(bias3 + cidx * 8)     = a;
        *(float4*)(bias3 + cidx * 8 + 4) = b;
        return;
    } else return;
    const float4* s4 = (const float4*)src;
    float4 a = s4[2 * c], b = s4[2 * c + 1];
    bf16x8 o;
    o[0] = (__bf16)a.x; o[1] = (__bf16)a.y; o[2] = (__bf16)a.z; o[3] = (__bf16)a.w;
    o[4] = (__bf16)b.x; o[5] = (__bf16)b.y; o[6] = (__bf16)b.z; o[7] = (__bf16)b.w;
    ((bf16x8*)dst)[c] = o;
}

// ---------------- NT bf16 GEMM: C[m,n] = sum_k A[m,k] * Bt[n,k] ------------
// 128x128 tile, BK=64, 4 waves (2x2 of 64x64), each wave 2x2 frags of 32x32,
// v_mfma_f32_32x32x16_bf16. LDS: 16B chunks, chunk (row,cs) holds cg=cs^(row&7).
// MODE 0: bf16 = acc + bias[n], scattered to C0/C1/C2 by n>>10 (fused QKV)
// MODE 1: f32  = acc * scale   (scores)
// MODE 2: f32  = acc           (PV)
template <int MODE>
__global__ __launch_bounds__(256, 3) void gemm_nt(
        const __bf16* __restrict__ A, const __bf16* __restrict__ Bt,
        void* __restrict__ C0, void* __restrict__ C1, void* __restrict__ C2,
        const float* __restrict__ bias,
        int lda, int ldb, int ldc, long sA, long sB, long sC,
        int K, float scale) {
    __shared__ __bf16 lA[128 * 64];
    __shared__ __bf16 lB[128 * 64];

    const int tid  = threadIdx.x;
    const int lane = tid & 63;
    const int wave = tid >> 6;
    const int mblk = blockIdx.y * 128;
    const int nblk = blockIdx.x * 128;
    const int z    = blockIdx.z;
    A  += (long)z * sA;
    Bt += (long)z * sB;

    const int wm = (wave >> 1) * 64;   // wave m offset in tile
    const int wn = (wave & 1) * 64;    // wave n offset in tile

    f32x16 acc[2][2];
#pragma unroll
    for (int i = 0; i < 2; ++i)
#pragma unroll
        for (int j = 0; j < 2; ++j)
#pragma unroll
            for (int r = 0; r < 16; ++r) acc[i][j][r] = 0.f;

    const int rowsel = lane & 31;      // row-in-32 selector for A/B frags
    const int khalf  = lane >> 5;      // k-chunk half selector (0/1)

    // staging addresses (swizzled source chunk per lane)
    int srow[4], scol[4];
#pragma unroll
    for (int it = 0; it < 4; ++it) {
        int s  = tid + it * 256;       // LDS slot 0..1023 (lane-ordered)
        srow[it] = s >> 3;
        scol[it] = ((s & 7) ^ (srow[it] & 7)) * 8;  // swizzled global col
    }

    for (int k0 = 0; k0 < K; k0 += 64) {
#pragma unroll
        for (int it = 0; it < 4; ++it) {
            int s = tid + it * 256;
            load_lds16(A  + (long)(mblk + srow[it]) * lda + k0 + scol[it], lA + s * 8);
            load_lds16(Bt + (long)(nblk + srow[it]) * ldb + k0 + scol[it], lB + s * 8);
        }
        __syncthreads();

#pragma unroll
        for (int kk = 0; kk < 4; ++kk) {           // 4 k-steps of 16
            const int cq = kk * 2 + khalf;         // needed global chunk col
            bf16x8 fa[2], fb[2];
#pragma unroll
            for (int t = 0; t < 2; ++t) {
                int ra = wm + t * 32 + rowsel;
                fa[t] = *(const bf16x8*)&lA[(ra * 8 + (cq ^ (ra & 7))) * 8];
                int rb = wn + t * 32 + rowsel;
                fb[t] = *(const bf16x8*)&lB[(rb * 8 + (cq ^ (rb & 7))) * 8];
            }
#pragma unroll
            for (int i = 0; i < 2; ++i)
#pragma unroll
                for (int j = 0; j < 2; ++j)
                    acc[i][j] = __builtin_amdgcn_mfma_f32_32x32x16_bf16(
                        fa[i], fb[j], acc[i][j], 0, 0, 0);
        }
        __syncthreads();
    }

    // epilogue: C/D layout: col = lane&31, row = (reg&3) + 8*(reg>>2) + 4*khalf
#pragma unroll
    for (int i = 0; i < 2; ++i) {
#pragma unroll
        for (int j = 0; j < 2; ++j) {
            const int n = nblk + wn + j * 32 + rowsel;
            if constexpr (MODE == 0) {
                __bf16* C = (n < 1024) ? (__bf16*)C0
                          : (n < 2048) ? (__bf16*)C1 : (__bf16*)C2;
                const int col = n & 1023;
                float bv = bias[n];
#pragma unroll
                for (int r = 0; r < 16; ++r) {
                    int m = mblk + wm + i * 32 + (r & 3) + 8 * (r >> 2) + 4 * khalf;
                    C[(long)m * ldc + col] = (__bf16)(acc[i][j][r] + bv);
                }
            } else if constexpr (MODE == 1) {
                float* C = (float*)C0 + (long)z * sC;
#pragma unroll
                for (int r = 0; r < 16; ++r) {
                    int m = mblk + wm + i * 32 + (r & 3) + 8 * (r >> 2) + 4 * khalf;
                    C[(long)m * ldc + n] = acc[i][j][r] * scale;
                }
            } else {
                float* C = (float*)C0 + (long)z * sC;
#pragma unroll
                for (int r = 0; r < 16; ++r) {
                    int m = mblk + wm + i * 32 + (r & 3) + 8 * (r >> 2) + 4 * khalf;
                    C[(long)m * ldc + n] = acc[i][j][r];
                }
            }
        }
    }
}

// ---------------- row softmax over 2048 floats, in-place + bf16 copy -------
__global__ __launch_bounds__(256) void softmax_rows(
        float* __restrict__ P, __bf16* __restrict__ Pb) {
    const long row = blockIdx.x;           // 8192 rows
    float*  p  = P  + row * 2048;
    __bf16* pb = Pb + row * 2048;
    const int tid  = threadIdx.x;
    const int lane = tid & 63;
    const int wave = tid >> 6;

    float4 v0 = ((const float4*)p)[tid * 2];
    float4 v1 = ((const float4*)p)[tid * 2 + 1];
    float e[8] = {v0.x, v0.y, v0.z, v0.w, v1.x, v1.y, v1.z, v1.w};

    float mx = e[0];
#pragma unroll
    for (int i = 1; i < 8; ++i) mx = fmaxf(mx, e[i]);
#pragma unroll
    for (int o = 1; o < 64; o <<= 1) mx = fmaxf(mx, __shfl_xor(mx, o, 64));

    __shared__ float redm[4], reds[4];
    if (lane == 0) redm[wave] = mx;
    __syncthreads();
    mx = fmaxf(fmaxf(redm[0], redm[1]), fmaxf(redm[2], redm[3]));

    float sum = 0.f;
#pragma unroll
    for (int i = 0; i < 8; ++i) { e[i] = __expf(e[i] - mx); sum += e[i]; }
#pragma unroll
    for (int o = 1; o < 64; o <<= 1) sum += __shfl_xor(sum, o, 64);
    if (lane == 0) reds[wave] = sum;
    __syncthreads();
    sum = reds[0] + reds[1] + reds[2] + reds[3];
    const float inv = 1.f / sum;

    float4 o0, o1;
    o0.x = e[0] * inv; o0.y = e[1] * inv; o0.z = e[2] * inv; o0.w = e[3] * inv;
    o1.x = e[4] * inv; o1.y = e[5] * inv; o1.z = e[6] * inv; o1.w = e[7] * inv;
    ((float4*)p)[tid * 2]     = o0;
    ((float4*)p)[tid * 2 + 1] = o1;
    bf16x8 ob;
    ob[0] = (__bf16)o0.x; ob[1] = (__bf16)o0.y; ob[2] = (__bf16)o0.z; ob[3] = (__bf16)o0.w;
    ob[4] = (__bf16)o1.x; ob[5] = (__bf16)o1.y; ob[6] = (__bf16)o1.z; ob[7] = (__bf16)o1.w;
    ((bf16x8*)pb)[tid] = ob;
}

// ---------------- bf16 transpose: V[b][t][h] -> Vt[b][h][t] ----------------
__global__ __launch_bounds__(256) void transpose_v(
        const __bf16* __restrict__ src, __bf16* __restrict__ dst) {
    __shared__ __bf16 t[32][33];
    const int tx = threadIdx.x, ty = threadIdx.y;   // (32, 8)
    const int tileC = blockIdx.x * 32;              // h base (0..1023)
    const int tileR = blockIdx.y * 32;              // t base (0..2047)
    const long zs = (long)blockIdx.z * 2048 * 1024;
    const long zd = (long)blockIdx.z * 1024 * 2048;
#pragma unroll
    for (int k = 0; k < 4; ++k) {
        int r = ty * 4 + k;
        t[r][tx] = src[zs + (long)(tileR + r) * 1024 + tileC + tx];
    }
    __syncthreads();
#pragma unroll
    for (int k = 0; k < 4; ++k) {
        int c = ty * 4 + k;
        dst[zd + (long)(tileC + c) * 2048 + tileR + tx] = t[tx][c];
    }
}

// ---------------------------------------------------------------------------
extern "C" void kernel_launch(void* const* d_in, const int* in_sizes, int n_in,
                              void* d_out, int out_size, void* d_ws, size_t ws_size,
                              hipStream_t stream) {
    const float* x  = (const float*)d_in[0];
    const float* Wq = (const float*)d_in[1];
    const float* bq = (const float*)d_in[2];
    const float* Wk = (const float*)d_in[3];
    const float* bk = (const float*)d_in[4];
    const float* Wv = (const float*)d_in[5];
    const float* bv = (const float*)d_in[6];

    const int  S = 2048, H = 1024, I = 1024, B = 4;
    const long MS = (long)B * S;              // 8192 rows
    float* out_ws  = (float*)d_out;                     // [B][S][H]
    float* out_att = (float*)d_out + (long)B * S * H;   // [B][S][S]

    char* w = (char*)d_ws;
    __bf16* x_bf   = (__bf16*)w; w += MS * I * 2;           // 16 MB
    __bf16* wqkv   = (__bf16*)w; w += (long)3 * H * I * 2;  //  6 MB
    float*  bias3  = (float*)w;  w += 4096 * 4;             // 16 KB
    __bf16* q_bf   = (__bf16*)w; w += MS * H * 2;           // 16 MB
    __bf16* k_bf   = (__bf16*)w; w += MS * H * 2;
    __bf16* v_bf   = (__bf16*)w; w += MS * H * 2;
    __bf16* vt_bf  = (__bf16*)w; w += MS * H * 2;
    __bf16* p_bf   = (__bf16*)w; w += (long)B * S * S * 2;  // 32 MB

    // 1) all converts + bias pack in one launch
    {
        long tot = 1048576 + 3 * 131072 + 384;   // chunks
        cvt_all<<<dim3((unsigned)((tot + 255) / 256)), dim3(256), 0, stream>>>(
            x, Wq, Wk, Wv, bq, bk, bv, x_bf, wqkv, bias3);
    }

    // 2) fused QKV projection: M=8192, N=3072, K=1024
    gemm_nt<0><<<dim3(24, 64, 1), dim3(256), 0, stream>>>(
        x_bf, wqkv, q_bf, k_bf, v_bf, bias3,
        1024, 1024, 1024, 0, 0, 0, 1024, 1.f);

    // 3) V transpose for PV GEMM
    transpose_v<<<dim3(32, 64, 4), dim3(32, 8), 0, stream>>>(v_bf, vt_bf);

    // 4) scores = Q K^T * 1/32 -> fp32 into attn-weights output region
    gemm_nt<1><<<dim3(16, 16, 4), dim3(256), 0, stream>>>(
        q_bf, k_bf, out_att, nullptr, nullptr, nullptr,
        1024, 1024, 2048, (long)S * H, (long)S * H, (long)S * S, 1024, 0.03125f);

    // 5) softmax rows in-place (+ bf16 copy for PV)
    softmax_rows<<<dim3(8192), dim3(256), 0, stream>>>(out_att, p_bf);

    // 6) weighted_sum = P V : M=2048, N=1024, K=2048 per batch
    gemm_nt<2><<<dim3(8, 16, 4), dim3(256), 0, stream>>>(
        p_bf, vt_bf, out_ws, nullptr, nullptr, nullptr,
        2048, 2048, 1024, (long)S * S, (long)S * H, (long)S * H, 2048, 1.f);
}

// Round 4
// 299.033 us; speedup vs baseline: 1.0753x; 1.0753x over previous
//
#include <hip/hip_runtime.h>
#include <hip/hip_bf16.h>
#include <cstdint>

// ---------------------------------------------------------------------------
// SelfAttention: q,k,v = x@W{q,k,v}^T + b ; P = softmax(qk^T/sqrt(H)) ; out = P@v
// B=4, S=2048, H=I=1024. fp32 I/O, bf16 MFMA internally (tol 6.25e-3).
// R4: back to 16x16x32 core (R3's 32x32 frag reads are structurally 4-way
//     bank-conflicted under lane-ordered global_load_lds staging).
//     V-transpose fused into QKV epilogue (LDS round-trip, swizzled).
//     launch_bounds (256,4).
// ---------------------------------------------------------------------------

typedef __bf16 bf16x8 __attribute__((ext_vector_type(8)));
typedef float  f32x4  __attribute__((ext_vector_type(4)));

__device__ __forceinline__ void load_lds16(const __bf16* g, __bf16* l) {
    __builtin_amdgcn_global_load_lds(
        (const __attribute__((address_space(1))) void*)g,
        (__attribute__((address_space(3))) void*)l,
        16, 0, 0);
}

// ------------- merged fp32->bf16 converts + bias pack (1 launch) -----------
__global__ __launch_bounds__(256) void cvt_all(
        const float* __restrict__ x,
        const float* __restrict__ wq, const float* __restrict__ wk,
        const float* __restrict__ wv,
        const float* __restrict__ bq, const float* __restrict__ bk,
        const float* __restrict__ bv,
        __bf16* __restrict__ xb, __bf16* __restrict__ wb,
        float* __restrict__ bias3) {
    const long NX = 1048576, NW = 131072;
    long i = (long)blockIdx.x * 256 + threadIdx.x;
    const float* src; __bf16* dst; long c;
    if (i < NX) { src = x; dst = xb; c = i; }
    else if (i < NX + 3 * NW) {
        long j = i - NX;
        src = (j < NW) ? wq : (j < 2 * NW) ? wk : wv;
        c = j % NW;
        dst = wb + (j / NW) * (NW * 8);
    } else if (i < NX + 3 * NW + 384) {
        long cidx = i - (NX + 3 * NW);
        int seg = (int)(cidx >> 7);
        const float* bs = (seg == 0) ? bq : (seg == 1) ? bk : bv;
        long off = (cidx & 127) * 8;
        float4 a = *(const float4*)(bs + off);
        float4 b = *(const float4*)(bs + off + 4);
        *(float4*)(bias3 + cidx * 8)     = a;
        *(float4*)(bias3 + cidx * 8 + 4) = b;
        return;
    } else return;
    const float4* s4 = (const float4*)src;
    float4 a = s4[2 * c], b = s4[2 * c + 1];
    bf16x8 o;
    o[0] = (__bf16)a.x; o[1] = (__bf16)a.y; o[2] = (__bf16)a.z; o[3] = (__bf16)a.w;
    o[4] = (__bf16)b.x; o[5] = (__bf16)b.y; o[6] = (__bf16)b.z; o[7] = (__bf16)b.w;
    ((bf16x8*)dst)[c] = o;
}

// ---------------- NT bf16 GEMM: C[m,n] = sum_k A[m,k] * Bt[n,k] ------------
// 128x128 tile, BK=64, 4 waves (2x2 of 64x64), 16x16x32 MFMA, 4x4 frags/wave.
// LDS: 16B chunks, chunk (row,cs) holds cg = cs ^ (row&7).  Zero conflicts.
// MODE 0: fused QKV. n<2048 -> bf16=acc+bias to C0/C1 [m][n&1023];
//         n>=2048 -> V: LDS-transposed, written as vt[h][t] to C2.
// MODE 1: f32 = acc * scale  (scores)
// MODE 2: f32 = acc          (PV)
template <int MODE>
__global__ __launch_bounds__(256, 4) void gemm_nt(
        const __bf16* __restrict__ A, const __bf16* __restrict__ Bt,
        void* __restrict__ C0, void* __restrict__ C1, void* __restrict__ C2,
        const float* __restrict__ bias,
        int lda, int ldb, int ldc, long sA, long sB, long sC,
        int K, float scale) {
    __shared__ __bf16 smem[16384];      // lA | lB, reused as transpose buffer
    __bf16* lA = smem;
    __bf16* lB = smem + 8192;

    const int tid  = threadIdx.x;
    const int lane = tid & 63;
    const int wave = tid >> 6;
    const int mblk = blockIdx.y * 128;
    const int nblk = blockIdx.x * 128;
    const int z    = blockIdx.z;
    A  += (long)z * sA;
    Bt += (long)z * sB;

    const int wm = (wave >> 1) * 64;
    const int wn = (wave & 1) * 64;

    f32x4 zero = {0.f, 0.f, 0.f, 0.f};
    f32x4 acc[4][4];
#pragma unroll
    for (int i = 0; i < 4; ++i)
#pragma unroll
        for (int j = 0; j < 4; ++j) acc[i][j] = zero;

    const int rsel = lane & 15;
    const int quad = lane >> 4;

    int srow[4], scol[4];
#pragma unroll
    for (int it = 0; it < 4; ++it) {
        int s  = tid + it * 256;
        srow[it] = s >> 3;
        scol[it] = ((s & 7) ^ (srow[it] & 7)) * 8;
    }

    for (int k0 = 0; k0 < K; k0 += 64) {
#pragma unroll
        for (int it = 0; it < 4; ++it) {
            int s = tid + it * 256;
            load_lds16(A  + (long)(mblk + srow[it]) * lda + k0 + scol[it], lA + s * 8);
            load_lds16(Bt + (long)(nblk + srow[it]) * ldb + k0 + scol[it], lB + s * 8);
        }
        __syncthreads();

#pragma unroll
        for (int half = 0; half < 2; ++half) {
            const int cq = quad + half * 4;
            bf16x8 fa[4], fb[4];
#pragma unroll
            for (int i = 0; i < 4; ++i) {
                int ra = wm + i * 16 + rsel;
                fa[i] = *(const bf16x8*)&lA[(ra * 8 + (cq ^ (ra & 7))) * 8];
                int rb = wn + i * 16 + rsel;
                fb[i] = *(const bf16x8*)&lB[(rb * 8 + (cq ^ (rb & 7))) * 8];
            }
#pragma unroll
            for (int i = 0; i < 4; ++i)
#pragma unroll
                for (int j = 0; j < 4; ++j)
                    acc[i][j] = __builtin_amdgcn_mfma_f32_16x16x32_bf16(
                        fa[i], fb[j], acc[i][j], 0, 0, 0);
        }
        __syncthreads();
    }

    // epilogue: lane holds C[m = wm+i*16+quad*4+r][n = wn+j*16+rsel]
    const int rq = quad * 4;
    if constexpr (MODE == 0) {
        if (nblk >= 2048) {
            // ---- V path: transpose tile via LDS, store vt[h][t] ----
            // tbuf element (n_loc, m_loc) at n_loc*128 + (chunk^ (n_loc&15))*8
            // + (m_loc&7).  Writes: b64 per (i,j); reads: b128 per chunk.
            __bf16* tbuf = smem;
#pragma unroll
            for (int i = 0; i < 4; ++i) {
#pragma unroll
                for (int j = 0; j < 4; ++j) {
                    const int n_loc = wn + j * 16 + rsel;
                    const float bv = bias[nblk + n_loc];
                    const int m_loc = wm + i * 16 + rq;       // +r, r=0..3
                    const int c  = m_loc >> 3;
                    const int cs = c ^ (n_loc & 15);
                    __bf16* dst = &tbuf[n_loc * 128 + cs * 8 + (m_loc & 7)];
                    __bf16 tmp[4];
#pragma unroll
                    for (int r = 0; r < 4; ++r) tmp[r] = (__bf16)(acc[i][j][r] + bv);
                    *(uint64_t*)dst = *(const uint64_t*)tmp;
                }
            }
            __syncthreads();
            // store: thread t -> row n_loc = t&127, chunk half cpart = t>>7
            {
                __bf16* vt = (__bf16*)C2;
                const int n_loc = tid & 127;
                const int cpart = tid >> 7;
                const long b = mblk >> 11;                    // batch
                const long t0 = mblk & 2047;
                const long h  = nblk - 2048 + n_loc;
                __bf16* gdst = vt + b * (1024L * 2048) + h * 2048 + t0;
#pragma unroll
                for (int s = 0; s < 8; ++s) {
                    int c  = cpart * 8 + s;
                    int cs = c ^ (n_loc & 15);
                    bf16x8 vchunk = *(const bf16x8*)&tbuf[n_loc * 128 + cs * 8];
                    *(bf16x8*)(gdst + c * 8) = vchunk;
                }
            }
        } else {
            // ---- Q/K path: normal [m][n] bf16 store ----
#pragma unroll
            for (int i = 0; i < 4; ++i) {
#pragma unroll
                for (int j = 0; j < 4; ++j) {
                    const int n = nblk + wn + j * 16 + rsel;
                    __bf16* C = (n < 1024) ? (__bf16*)C0 : (__bf16*)C1;
                    const int col = n & 1023;
                    float bv = bias[n];
#pragma unroll
                    for (int r = 0; r < 4; ++r) {
                        int m = mblk + wm + i * 16 + rq + r;
                        C[(long)m * ldc + col] = (__bf16)(acc[i][j][r] + bv);
                    }
                }
            }
        }
    } else {
#pragma unroll
        for (int i = 0; i < 4; ++i) {
#pragma unroll
            for (int j = 0; j < 4; ++j) {
                const int n = nblk + wn + j * 16 + rsel;
                float* C = (float*)C0 + (long)z * sC;
                if constexpr (MODE == 1) {
#pragma unroll
                    for (int r = 0; r < 4; ++r) {
                        int m = mblk + wm + i * 16 + rq + r;
                        C[(long)m * ldc + n] = acc[i][j][r] * scale;
                    }
                } else {
#pragma unroll
                    for (int r = 0; r < 4; ++r) {
                        int m = mblk + wm + i * 16 + rq + r;
                        C[(long)m * ldc + n] = acc[i][j][r];
                    }
                }
            }
        }
    }
}

// ---------------- row softmax over 2048 floats, in-place + bf16 copy -------
__global__ __launch_bounds__(256) void softmax_rows(
        float* __restrict__ P, __bf16* __restrict__ Pb) {
    const long row = blockIdx.x;
    float*  p  = P  + row * 2048;
    __bf16* pb = Pb + row * 2048;
    const int tid  = threadIdx.x;
    const int lane = tid & 63;
    const int wave = tid >> 6;

    float4 v0 = ((const float4*)p)[tid * 2];
    float4 v1 = ((const float4*)p)[tid * 2 + 1];
    float e[8] = {v0.x, v0.y, v0.z, v0.w, v1.x, v1.y, v1.z, v1.w};

    float mx = e[0];
#pragma unroll
    for (int i = 1; i < 8; ++i) mx = fmaxf(mx, e[i]);
#pragma unroll
    for (int o = 1; o < 64; o <<= 1) mx = fmaxf(mx, __shfl_xor(mx, o, 64));

    __shared__ float redm[4], reds[4];
    if (lane == 0) redm[wave] = mx;
    __syncthreads();
    mx = fmaxf(fmaxf(redm[0], redm[1]), fmaxf(redm[2], redm[3]));

    float sum = 0.f;
#pragma unroll
    for (int i = 0; i < 8; ++i) { e[i] = __expf(e[i] - mx); sum += e[i]; }
#pragma unroll
    for (int o = 1; o < 64; o <<= 1) sum += __shfl_xor(sum, o, 64);
    if (lane == 0) reds[wave] = sum;
    __syncthreads();
    sum = reds[0] + reds[1] + reds[2] + reds[3];
    const float inv = 1.f / sum;

    float4 o0, o1;
    o0.x = e[0] * inv; o0.y = e[1] * inv; o0.z = e[2] * inv; o0.w = e[3] * inv;
    o1.x = e[4] * inv; o1.y = e[5] * inv; o1.z = e[6] * inv; o1.w = e[7] * inv;
    ((float4*)p)[tid * 2]     = o0;
    ((float4*)p)[tid * 2 + 1] = o1;
    bf16x8 ob;
    ob[0] = (__bf16)o0.x; ob[1] = (__bf16)o0.y; ob[2] = (__bf16)o0.z; ob[3] = (__bf16)o0.w;
    ob[4] = (__bf16)o1.x; ob[5] = (__bf16)o1.y; ob[6] = (__bf16)o1.z; ob[7] = (__bf16)o1.w;
    ((bf16x8*)pb)[tid] = ob;
}

// ---------------------------------------------------------------------------
extern "C" void kernel_launch(void* const* d_in, const int* in_sizes, int n_in,
                              void* d_out, int out_size, void* d_ws, size_t ws_size,
                              hipStream_t stream) {
    const float* x  = (const float*)d_in[0];
    const float* Wq = (const float*)d_in[1];
    const float* bq = (const float*)d_in[2];
    const float* Wk = (const float*)d_in[3];
    const float* bk = (const float*)d_in[4];
    const float* Wv = (const float*)d_in[5];
    const float* bv = (const float*)d_in[6];

    const int  S = 2048, H = 1024, I = 1024, B = 4;
    const long MS = (long)B * S;
    float* out_ws  = (float*)d_out;
    float* out_att = (float*)d_out + (long)B * S * H;

    char* w = (char*)d_ws;
    __bf16* x_bf   = (__bf16*)w; w += MS * I * 2;
    __bf16* wqkv   = (__bf16*)w; w += (long)3 * H * I * 2;
    float*  bias3  = (float*)w;  w += 4096 * 4;
    __bf16* q_bf   = (__bf16*)w; w += MS * H * 2;
    __bf16* k_bf   = (__bf16*)w; w += MS * H * 2;
    __bf16* vt_bf  = (__bf16*)w; w += MS * H * 2;
    __bf16* p_bf   = (__bf16*)w; w += (long)B * S * S * 2;

    // 1) all converts + bias pack
    {
        long tot = 1048576 + 3 * 131072 + 384;
        cvt_all<<<dim3((unsigned)((tot + 255) / 256)), dim3(256), 0, stream>>>(
            x, Wq, Wk, Wv, bq, bk, bv, x_bf, wqkv, bias3);
    }

    // 2) fused QKV projection (V written pre-transposed): M=8192, N=3072, K=1024
    gemm_nt<0><<<dim3(24, 64, 1), dim3(256), 0, stream>>>(
        x_bf, wqkv, q_bf, k_bf, vt_bf, bias3,
        1024, 1024, 1024, 0, 0, 0, 1024, 1.f);

    // 3) scores = Q K^T * 1/32 -> fp32 into attn-weights output region
    gemm_nt<1><<<dim3(16, 16, 4), dim3(256), 0, stream>>>(
        q_bf, k_bf, out_att, nullptr, nullptr, nullptr,
        1024, 1024, 2048, (long)S * H, (long)S * H, (long)S * S, 1024, 0.03125f);

    // 4) softmax rows in-place (+ bf16 copy for PV)
    softmax_rows<<<dim3(8192), dim3(256), 0, stream>>>(out_att, p_bf);

    // 5) weighted_sum = P V : M=2048, N=1024, K=2048 per batch
    gemm_nt<2><<<dim3(8, 16, 4), dim3(256), 0, stream>>>(
        p_bf, vt_bf, out_ws, nullptr, nullptr, nullptr,
        2048, 2048, 1024, (long)S * S, (long)S * H, (long)S * H, 2048, 1.f);
}